// Round 1
// baseline (303.380 us; speedup 1.0000x reference)
//
#include <hip/hip_runtime.h>
#include <math.h>

// Problem constants
constexpr int B_  = 2;
constexpr int C_  = 256;
constexpr int CQ_ = 64;
constexpr int N_  = 4096;  // 64*64

typedef __attribute__((ext_vector_type(8))) short     short8;  // 8 bf16
typedef __attribute__((ext_vector_type(8))) _Float16  half8;   // 8 f16
typedef __attribute__((ext_vector_type(4))) float     f32x4;   // MFMA C/D

constexpr float SHIFT = 24.0f;   // static softmax shift (exact: shift-invariance)

static __device__ __forceinline__ unsigned short f2bf(float x) {
    union { float f; unsigned u; } v; v.f = x;
    unsigned r = (v.u + 0x7FFFu + ((v.u >> 16) & 1u)) >> 16;  // RNE
    return (unsigned short)r;
}

// ---------------------------------------------------------------------------
// Weight convert: fp32 -> f16, concat [q1|k1|v1|q2|k2|v2] (96K elems/stream)
// ---------------------------------------------------------------------------
__global__ __launch_bounds__(256)
void wconv_kernel(const float* __restrict__ q1w, const float* __restrict__ k1w,
                  const float* __restrict__ v1w, const float* __restrict__ q2w,
                  const float* __restrict__ k2w, const float* __restrict__ v2w,
                  _Float16* __restrict__ wb)
{
    int i = (blockIdx.x * 256 + threadIdx.x) * 4;   // grid 192 -> 196608 elems
    const float* src;
    int off;
    if      (i < 16384)  { src = q1w; off = 0; }
    else if (i < 32768)  { src = k1w; off = 16384; }
    else if (i < 98304)  { src = v1w; off = 32768; }
    else if (i < 114688) { src = q2w; off = 98304; }
    else if (i < 131072) { src = k2w; off = 114688; }
    else                 { src = v2w; off = 131072; }
    float4 f = *(const float4*)(src + (i - off));
    _Float16 h0 = (_Float16)f.x, h1 = (_Float16)f.y;
    _Float16 h2 = (_Float16)f.z, h3 = (_Float16)f.w;
    ushort4 u;
    u.x = *(unsigned short*)&h0; u.y = *(unsigned short*)&h1;
    u.z = *(unsigned short*)&h2; u.w = *(unsigned short*)&h3;
    *(ushort4*)((unsigned short*)wb + i) = u;
}

// ---------------------------------------------------------------------------
// Fused QKV projection (MFMA, f16 inputs, fp32 accum).
// v2: n-tile 32 (was 64) -> grid (128,4) = 512 blocks = 2 blocks/CU.
// Per block: stage X[c][n] fp32 -> Xs[n][c] f16 once (32n x 256c).
// Q/K: waves 0-3 -> Q, 4-7 -> K; each wave = (nb = w&1, opair = (w>>1)&1).
// V:   wave owns c-block 32*wave, n-subtiles 0..1.
// ---------------------------------------------------------------------------
__global__ __launch_bounds__(512, 4)
void proj_kernel(const float* __restrict__ in1, const float* __restrict__ in2,
                 const _Float16* __restrict__ wb,
                 const float* __restrict__ q1b, const float* __restrict__ k1b,
                 const float* __restrict__ v1b, const float* __restrict__ q2b,
                 const float* __restrict__ k2b, const float* __restrict__ v2b,
                 _Float16* __restrict__ q_ws, _Float16* __restrict__ k_ws,
                 unsigned short* __restrict__ v_ws)
{
    __shared__ _Float16 Xs[32 * 264];
    const int bs = blockIdx.y, s = bs >> 1, bb = bs & 1;
    const int n0 = blockIdx.x * 32;
    const float* x = (s ? in2 : in1) + (size_t)bb * C_ * N_;
    const int tid = threadIdx.x;
    const int lane = tid & 63, wave = tid >> 6, quad = lane >> 4, l15 = lane & 15;

    // stage + transpose + convert X tile (256c x 32n)
    #pragma unroll
    for (int rep = 0; rep < 4; ++rep) {
        int idx = rep * 512 + tid;
        int c = idx >> 3, ng = idx & 7;
        float4 f = *(const float4*)(x + (size_t)c * N_ + n0 + ng * 4);
        Xs[(ng * 4 + 0) * 264 + c] = (_Float16)f.x;
        Xs[(ng * 4 + 1) * 264 + c] = (_Float16)f.y;
        Xs[(ng * 4 + 2) * 264 + c] = (_Float16)f.z;
        Xs[(ng * 4 + 3) * 264 + c] = (_Float16)f.w;
    }
    __syncthreads();

    const _Float16* wqs = wb + (size_t)s * 98304;
    const _Float16* wks = wqs + 16384;
    const _Float16* wvs = wks + 16384;

    // ---- Q/K ----
    {
        const int m = wave >> 2;
        const int nb = wave & 1, opair = (wave >> 1) & 1;
        const _Float16* W = m ? wks : wqs;
        const float* bias = m ? (s ? k2b : k1b) : (s ? q2b : q1b);
        _Float16* outp = (m ? k_ws : q_ws) + (size_t)bs * N_ * CQ_;
        half8 af[8];
        #pragma unroll
        for (int kh = 0; kh < 8; ++kh)
            af[kh] = *(const half8*)(&Xs[(16 * nb + l15) * 264 + quad * 8 + kh * 32]);
        f32x4 a4[2];
        #pragma unroll
        for (int oo = 0; oo < 2; ++oo) a4[oo] = (f32x4){0.f, 0.f, 0.f, 0.f};
        #pragma unroll
        for (int kh = 0; kh < 8; ++kh)
            #pragma unroll
            for (int oo = 0; oo < 2; ++oo) {
                int o = 2 * opair + oo;
                half8 bf = *(const half8*)(W + (size_t)(16 * o + l15) * C_ + quad * 8 + kh * 32);
                a4[oo] = __builtin_amdgcn_mfma_f32_16x16x32_f16(af[kh], bf, a4[oo], 0, 0, 0);
            }
        #pragma unroll
        for (int oo = 0; oo < 2; ++oo) {
            int o = 2 * opair + oo;
            float bv = bias[16 * o + l15];
            #pragma unroll
            for (int r = 0; r < 4; ++r) {
                int n = n0 + 16 * nb + quad * 4 + r;
                outp[(size_t)n * CQ_ + 16 * o + l15] = (_Float16)(a4[oo][r] + bv);
            }
        }
    }

    // ---- V: wave owns c-block 32*wave .. +31, n-subtiles 0..1 ----
    {
        const float* vb = s ? v2b : v1b;
        unsigned short* outp = v_ws + (size_t)bs * C_ * N_;
        f32x4 v4[2][2];
        #pragma unroll
        for (int o = 0; o < 2; ++o)
            #pragma unroll
            for (int nt = 0; nt < 2; ++nt) v4[o][nt] = (f32x4){0.f, 0.f, 0.f, 0.f};
        #pragma unroll
        for (int kh = 0; kh < 8; ++kh) {
            half8 bf[2], af[2];
            #pragma unroll
            for (int nt = 0; nt < 2; ++nt)
                bf[nt] = *(const half8*)(&Xs[(16 * nt + l15) * 264 + quad * 8 + kh * 32]);
            #pragma unroll
            for (int o = 0; o < 2; ++o)
                af[o] = *(const half8*)(wvs + (size_t)(32 * wave + 16 * o + l15) * C_ + quad * 8 + kh * 32);
            #pragma unroll
            for (int o = 0; o < 2; ++o)
                #pragma unroll
                for (int nt = 0; nt < 2; ++nt)
                    v4[o][nt] = __builtin_amdgcn_mfma_f32_16x16x32_f16(af[o], bf[nt], v4[o][nt], 0, 0, 0);
        }
        #pragma unroll
        for (int o = 0; o < 2; ++o)
            #pragma unroll
            for (int r = 0; r < 4; ++r) {
                int c = 32 * wave + 16 * o + quad * 4 + r;
                float bv = vb[c];
                #pragma unroll
                for (int nt = 0; nt < 2; ++nt)
                    outp[(size_t)c * N_ + n0 + 16 * nt + l15] = f2bf(v4[o][nt][r] + bv);
            }
    }
}

// ---------------------------------------------------------------------------
// MFMA flash attention, static-shift softmax (no online state).
// v2: TQ=32 (was 64) -> grid 512 blocks = 2 blocks/CU (16 waves/CU) so one
// block's __syncthreads/latency stalls overlap the other block's MFMA.
// WG = 512 thr / 8 waves, TJ=64 per iter.  K/V fragments loaded DIRECTLY
// from global (L2-resident per XCD); only P round-trips LDS (double-buffered
// -> 1 barrier/iter).
// S waves: jsub=w&3, isub=w>>2 (one 16x16 tile of S^T[64j][32i] each).
// PV waves: wc=w (32i x 32c).  l_i accumulated per-thread, reduced once.
// ---------------------------------------------------------------------------
constexpr int ST = 72;   // Pt stride (bf16 elems)

__global__ __launch_bounds__(512, 4)
void flash_kernel(const _Float16* __restrict__ qg,        // [bs][n][64] f16
                  const _Float16* __restrict__ kg,        // [bs][n][64] f16
                  const unsigned short* __restrict__ vg,  // [bs][c][n] bf16
                  const float* __restrict__ in1, const float* __restrict__ in2,
                  const float* __restrict__ gamma_p, float* __restrict__ out)
{
    __shared__ unsigned short Pt[2][32 * ST];
    __shared__ float lsum[32 * 4];

    const int tid  = threadIdx.x;
    const int lane = tid & 63;
    const int wave = tid >> 6;
    const int quad = lane >> 4;
    const int l15  = lane & 15;
    const int bs   = blockIdx.x & 3;        // bs interleaved across XCDs (L2 locality)
    const int q0   = (blockIdx.x >> 2) * 32;
    const int s = bs >> 1, bb = bs & 1;
    const int jsub = wave & 3;
    const int isub = wave >> 2;             // S-phase i-subtile of this wave
    const int wc   = wave;                  // PV: c-block 32*wc

    const _Float16* qp = qg + (size_t)bs * N_ * CQ_;
    const _Float16* kp = kg + (size_t)bs * N_ * CQ_;
    const unsigned short* vp = vg + (size_t)bs * C_ * N_;

    // persistent Q B-frags (i = 16*isub + l15)
    half8 qf[2];
    #pragma unroll
    for (int kh = 0; kh < 2; ++kh)
        qf[kh] = *(const half8*)(
            qp + (size_t)(q0 + 16 * isub + l15) * CQ_ + quad * 8 + kh * 32);

    float lacc = 0.f;
    f32x4 acc[2][2];   // [is2: i=16*is2+quad*4+r][csub: c=32wc+16csub+l15]
    #pragma unroll
    for (int a = 0; a < 2; ++a)
        #pragma unroll
        for (int b = 0; b < 2; ++b) acc[a][b] = (f32x4){0.f, 0.f, 0.f, 0.f};

    // K A-frag prefetch for iter 0 (j = 16*jsub + l15)
    half8 kf[2];
    #pragma unroll
    for (int kh = 0; kh < 2; ++kh)
        kf[kh] = *(const half8*)(kp + (size_t)(16 * jsub + l15) * CQ_ + quad * 8 + kh * 32);

    for (int jt = 0; jt < N_; jt += 64) {
        const int pb = (jt >> 6) & 1;
        // V B-frags for this iter (consumed after barrier; latency hidden by S)
        short8 vf[2][2];
        #pragma unroll
        for (int csub = 0; csub < 2; ++csub)
            #pragma unroll
            for (int kh = 0; kh < 2; ++kh)
                vf[csub][kh] = *(const short8*)(
                    vp + (size_t)(32 * wc + 16 * csub + l15) * N_ + jt + quad * 8 + kh * 32);
        // K prefetch for next iter
        int jn = (jt + 64 < N_) ? jt + 64 : 0;
        half8 kn0 = *(const half8*)(kp + (size_t)(jn + 16 * jsub + l15) * CQ_ + quad * 8);
        half8 kn1 = *(const half8*)(kp + (size_t)(jn + 16 * jsub + l15) * CQ_ + quad * 8 + 32);

        // ---- S: S^T[j=16jsub+quad*4+r][i=16isub+l15] ----
        f32x4 sacc = (f32x4){0.f, 0.f, 0.f, 0.f};
        #pragma unroll
        for (int kh = 0; kh < 2; ++kh)
            sacc = __builtin_amdgcn_mfma_f32_16x16x32_f16(kf[kh], qf[kh], sacc, 0, 0, 0);

        // p = exp(s - SHIFT); accumulate l; write P[i][j] (bf16, b64)
        {
            f32x4 p;
            p.x = __expf(sacc.x - SHIFT);
            p.y = __expf(sacc.y - SHIFT);
            p.z = __expf(sacc.z - SHIFT);
            p.w = __expf(sacc.w - SHIFT);
            lacc += p.x + p.y + p.z + p.w;
            ushort4 pbv;
            pbv.x = f2bf(p.x); pbv.y = f2bf(p.y); pbv.z = f2bf(p.z); pbv.w = f2bf(p.w);
            *(ushort4*)(&Pt[pb][(16 * isub + l15) * ST + 16 * jsub + quad * 4]) = pbv;
        }
        kf[0] = kn0; kf[1] = kn1;
        __syncthreads();

        // ---- PV: O^T[i=16is2+quad*4+r][c=32wc+16csub+l15] ----
        short8 ap[2][2];
        #pragma unroll
        for (int is2 = 0; is2 < 2; ++is2)
            #pragma unroll
            for (int kh = 0; kh < 2; ++kh)
                ap[is2][kh] = *(const short8*)(
                    &Pt[pb][(16 * is2 + l15) * ST + quad * 8 + kh * 32]);
        #pragma unroll
        for (int kh = 0; kh < 2; ++kh)
            #pragma unroll
            for (int is2 = 0; is2 < 2; ++is2)
                #pragma unroll
                for (int csub = 0; csub < 2; ++csub)
                    acc[is2][csub] = __builtin_amdgcn_mfma_f32_16x16x32_bf16(
                        ap[is2][kh], vf[csub][kh], acc[is2][csub], 0, 0, 0);
    }

    // ---- l reduction (once): quad-shfl then cross-jsub via LDS ----
    {
        float t = lacc;
        t += __shfl_xor(t, 16);
        t += __shfl_xor(t, 32);
        if (quad == 0)
            lsum[(16 * isub + l15) * 4 + jsub] = t;
    }
    __syncthreads();

    const float gamma = gamma_p[0];
    const float* inp = (s ? in2 : in1) + (size_t)bb * C_ * N_;
    float* op = out + (size_t)bs * C_ * N_;
    #pragma unroll
    for (int is2 = 0; is2 < 2; ++is2) {
        float inv[4];
        #pragma unroll
        for (int r = 0; r < 4; ++r) {
            f32x4 t = *(f32x4*)(&lsum[(16 * is2 + quad * 4 + r) * 4]);
            inv[r] = 1.0f / (t.x + t.y + t.z + t.w);
        }
        #pragma unroll
        for (int csub = 0; csub < 2; ++csub) {
            int c = 32 * wc + 16 * csub + l15;
            #pragma unroll
            for (int r = 0; r < 4; ++r) {
                int i = q0 + 16 * is2 + quad * 4 + r;
                size_t idx = (size_t)c * N_ + i;
                op[idx] = gamma * acc[is2][csub][r] * inv[r] + inp[idx];
            }
        }
    }
}

// ---------------------------------------------------------------------------
extern "C" void kernel_launch(void* const* d_in, const int* in_sizes, int n_in,
                              void* d_out, int out_size, void* d_ws, size_t ws_size,
                              hipStream_t stream)
{
    const float* in1 = (const float*)d_in[0];
    const float* in2 = (const float*)d_in[1];
    const float* q1w = (const float*)d_in[2];
    const float* q1b = (const float*)d_in[3];
    const float* k1w = (const float*)d_in[4];
    const float* k1b = (const float*)d_in[5];
    const float* v1w = (const float*)d_in[6];
    const float* v1b = (const float*)d_in[7];
    const float* q2w = (const float*)d_in[8];
    const float* q2b = (const float*)d_in[9];
    const float* k2w = (const float*)d_in[10];
    const float* k2b = (const float*)d_in[11];
    const float* v2w = (const float*)d_in[12];
    const float* v2b = (const float*)d_in[13];
    const float* gamma = (const float*)d_in[22];
    float* out = (float*)d_out;

    // ws: wb f16 196608 | q[4][4096][64] f16 | k same | v[4][256][4096] bf16
    _Float16* wb   = (_Float16*)d_ws;
    _Float16* q_ws = wb + 196608;
    _Float16* k_ws = q_ws + (size_t)4 * N_ * CQ_;
    unsigned short* v_ws = (unsigned short*)(k_ws + (size_t)4 * N_ * CQ_);

    wconv_kernel<<<dim3(192), 256, 0, stream>>>(q1w, k1w, v1w, q2w, k2w, v2w, wb);
    proj_kernel<<<dim3(128, 4), 512, 0, stream>>>(
        in1, in2, wb, q1b, k1b, v1b, q2b, k2b, v2b, q_ws, k_ws, v_ws);
    flash_kernel<<<dim3(512), 512, 0, stream>>>(q_ws, k_ws, v_ws, in1, in2, gamma, out);
}

// Round 2
// 222.321 us; speedup vs baseline: 1.3646x; 1.3646x over previous
//
#include <hip/hip_runtime.h>
#include <math.h>

// Problem constants
constexpr int B_  = 2;
constexpr int C_  = 256;
constexpr int CQ_ = 64;
constexpr int N_  = 4096;  // 64*64

typedef __attribute__((ext_vector_type(8))) short     short8;  // 8 bf16
typedef __attribute__((ext_vector_type(8))) _Float16  half8;   // 8 f16
typedef __attribute__((ext_vector_type(4))) float     f32x4;   // MFMA C/D

constexpr float SHIFT = 24.0f;   // static softmax shift (exact: shift-invariance)

static __device__ __forceinline__ unsigned short f2bf(float x) {
    union { float f; unsigned u; } v; v.f = x;
    unsigned r = (v.u + 0x7FFFu + ((v.u >> 16) & 1u)) >> 16;  // RNE
    return (unsigned short)r;
}

// ---------------------------------------------------------------------------
// Weight convert: fp32 -> f16, concat [q1|k1|v1|q2|k2|v2] (96K elems/stream)
// ---------------------------------------------------------------------------
__global__ __launch_bounds__(256)
void wconv_kernel(const float* __restrict__ q1w, const float* __restrict__ k1w,
                  const float* __restrict__ v1w, const float* __restrict__ q2w,
                  const float* __restrict__ k2w, const float* __restrict__ v2w,
                  _Float16* __restrict__ wb)
{
    int i = (blockIdx.x * 256 + threadIdx.x) * 4;   // grid 192 -> 196608 elems
    const float* src;
    int off;
    if      (i < 16384)  { src = q1w; off = 0; }
    else if (i < 32768)  { src = k1w; off = 16384; }
    else if (i < 98304)  { src = v1w; off = 32768; }
    else if (i < 114688) { src = q2w; off = 98304; }
    else if (i < 131072) { src = k2w; off = 114688; }
    else                 { src = v2w; off = 131072; }
    float4 f = *(const float4*)(src + (i - off));
    _Float16 h0 = (_Float16)f.x, h1 = (_Float16)f.y;
    _Float16 h2 = (_Float16)f.z, h3 = (_Float16)f.w;
    ushort4 u;
    u.x = *(unsigned short*)&h0; u.y = *(unsigned short*)&h1;
    u.z = *(unsigned short*)&h2; u.w = *(unsigned short*)&h3;
    *(ushort4*)((unsigned short*)wb + i) = u;
}

// ---------------------------------------------------------------------------
// Fused QKV projection (MFMA, f16 inputs, fp32 accum).  (round-0 structure)
// Per block: one 64-n tile of one bs.  Stage X[c][n] fp32 -> Xs[n][c] f16 once.
// Q,K -> [bs][n][64] f16; V -> [bs][c][n] bf16.
// ---------------------------------------------------------------------------
__global__ __launch_bounds__(512)
void proj_kernel(const float* __restrict__ in1, const float* __restrict__ in2,
                 const _Float16* __restrict__ wb,
                 const float* __restrict__ q1b, const float* __restrict__ k1b,
                 const float* __restrict__ v1b, const float* __restrict__ q2b,
                 const float* __restrict__ k2b, const float* __restrict__ v2b,
                 _Float16* __restrict__ q_ws, _Float16* __restrict__ k_ws,
                 unsigned short* __restrict__ v_ws)
{
    __shared__ _Float16 Xs[64 * 264];
    const int bs = blockIdx.y, s = bs >> 1, bb = bs & 1;
    const int n0 = blockIdx.x * 64;
    const float* x = (s ? in2 : in1) + (size_t)bb * C_ * N_;
    const int tid = threadIdx.x;
    const int lane = tid & 63, wave = tid >> 6, quad = lane >> 4, l15 = lane & 15;

    // stage + transpose + convert X tile (256c x 64n)
    #pragma unroll
    for (int rep = 0; rep < 8; ++rep) {
        int idx = rep * 512 + tid;
        int c = idx >> 4, ng = idx & 15;
        float4 f = *(const float4*)(x + (size_t)c * N_ + n0 + ng * 4);
        Xs[(ng * 4 + 0) * 264 + c] = (_Float16)f.x;
        Xs[(ng * 4 + 1) * 264 + c] = (_Float16)f.y;
        Xs[(ng * 4 + 2) * 264 + c] = (_Float16)f.z;
        Xs[(ng * 4 + 3) * 264 + c] = (_Float16)f.w;
    }
    __syncthreads();

    const _Float16* wqs = wb + (size_t)s * 98304;
    const _Float16* wks = wqs + 16384;
    const _Float16* wvs = wks + 16384;

    // ---- Q/K: waves 0-3 -> Q, 4-7 -> K; n-block = wave&3 ----
    {
        const int m = wave >> 2, nb = wave & 3;
        const _Float16* W = m ? wks : wqs;
        const float* bias = m ? (s ? k2b : k1b) : (s ? q2b : q1b);
        _Float16* outp = (m ? k_ws : q_ws) + (size_t)bs * N_ * CQ_;
        half8 af[8];
        #pragma unroll
        for (int kh = 0; kh < 8; ++kh)
            af[kh] = *(const half8*)(&Xs[(16 * nb + l15) * 264 + quad * 8 + kh * 32]);
        f32x4 a4[4];
        #pragma unroll
        for (int o = 0; o < 4; ++o) a4[o] = (f32x4){0.f, 0.f, 0.f, 0.f};
        #pragma unroll
        for (int kh = 0; kh < 8; ++kh)
            #pragma unroll
            for (int o = 0; o < 4; ++o) {
                half8 bf = *(const half8*)(W + (size_t)(16 * o + l15) * C_ + quad * 8 + kh * 32);
                a4[o] = __builtin_amdgcn_mfma_f32_16x16x32_f16(af[kh], bf, a4[o], 0, 0, 0);
            }
        #pragma unroll
        for (int o = 0; o < 4; ++o) {
            float bv = bias[16 * o + l15];
            #pragma unroll
            for (int r = 0; r < 4; ++r) {
                int n = n0 + 16 * nb + quad * 4 + r;
                outp[(size_t)n * CQ_ + 16 * o + l15] = (_Float16)(a4[o][r] + bv);
            }
        }
    }

    // ---- V: wave owns o-block 32*wave .. +31 ----
    {
        const float* vb = s ? v2b : v1b;
        unsigned short* outp = v_ws + (size_t)bs * C_ * N_;
        f32x4 v4[2][4];
        #pragma unroll
        for (int o = 0; o < 2; ++o)
            #pragma unroll
            for (int nt = 0; nt < 4; ++nt) v4[o][nt] = (f32x4){0.f, 0.f, 0.f, 0.f};
        #pragma unroll
        for (int kh = 0; kh < 8; ++kh) {
            half8 bf[4], af[2];
            #pragma unroll
            for (int nt = 0; nt < 4; ++nt)
                bf[nt] = *(const half8*)(&Xs[(16 * nt + l15) * 264 + quad * 8 + kh * 32]);
            #pragma unroll
            for (int o = 0; o < 2; ++o)
                af[o] = *(const half8*)(wvs + (size_t)(32 * wave + 16 * o + l15) * C_ + quad * 8 + kh * 32);
            #pragma unroll
            for (int o = 0; o < 2; ++o)
                #pragma unroll
                for (int nt = 0; nt < 4; ++nt)
                    v4[o][nt] = __builtin_amdgcn_mfma_f32_16x16x32_f16(af[o], bf[nt], v4[o][nt], 0, 0, 0);
        }
        #pragma unroll
        for (int o = 0; o < 2; ++o)
            #pragma unroll
            for (int r = 0; r < 4; ++r) {
                int c = 32 * wave + 16 * o + quad * 4 + r;
                float bv = vb[c];
                #pragma unroll
                for (int nt = 0; nt < 4; ++nt)
                    outp[(size_t)c * N_ + n0 + 16 * nt + l15] = f2bf(v4[o][nt][r] + bv);
            }
    }
}

// ---------------------------------------------------------------------------
// MFMA flash attention, static-shift softmax (no online state).
// v3 (from round-0 TQ=64 base):
//  (a) counted-vmcnt barrier: s_waitcnt lgkmcnt(0) + raw s_barrier instead of
//      __syncthreads().  The full drain (vmcnt(0)) was serializing every iter:
//      next-iter K prefetch and in-flight V loads were forced to complete at
//      the barrier instead of riding through into the PV phase.  Only the LDS
//      P-traffic needs draining (lgkmcnt); K/V register loads are wave-private.
//  (b) XOR-swizzled Pt (byte ^= (row&7)<<4, stride 128B): the padded ST=72
//      layout left 8 lanes per 4-bank group on the PV ds_read_b128
//      (5.2M conflict cycles); the swizzle is bank-balanced at min phases.
// WG = 512 thr / 8 waves, TQ=64, TJ=64, grid 256 (1 block/CU, grid-limited).
// S waves: jsub=w&3, ihalf=w>>2 (S^T[16j][32i]).  PV waves: wc=w (64i x 32c).
// ---------------------------------------------------------------------------
__global__ __launch_bounds__(512)
void flash_kernel(const _Float16* __restrict__ qg,        // [bs][n][64] f16
                  const _Float16* __restrict__ kg,        // [bs][n][64] f16
                  const unsigned short* __restrict__ vg,  // [bs][c][n] bf16
                  const float* __restrict__ in1, const float* __restrict__ in2,
                  const float* __restrict__ gamma_p, float* __restrict__ out)
{
    __shared__ unsigned short Pt[2][64 * 64];   // swizzled, 128 B/row
    __shared__ float lsum[64 * 4];

    const int tid  = threadIdx.x;
    const int lane = tid & 63;
    const int wave = tid >> 6;
    const int quad = lane >> 4;
    const int l15  = lane & 15;
    const int bs   = blockIdx.x & 3;        // one bs per XCD-pair (L2 locality)
    const int q0   = (blockIdx.x >> 2) * 64;
    const int s = bs >> 1, bb = bs & 1;
    const int jsub  = wave & 3;
    const int ihalf = wave >> 2;
    const int wc    = wave;                 // PV: c-block 32*wc

    const _Float16* qp = qg + (size_t)bs * N_ * CQ_;
    const _Float16* kp = kg + (size_t)bs * N_ * CQ_;
    const unsigned short* vp = vg + (size_t)bs * C_ * N_;

    // persistent Q B-frags (i = 32*ihalf + 16*isub + l15)
    half8 qf[2][2];
    #pragma unroll
    for (int isub = 0; isub < 2; ++isub)
        #pragma unroll
        for (int kh = 0; kh < 2; ++kh)
            qf[isub][kh] = *(const half8*)(
                qp + (size_t)(q0 + 32 * ihalf + 16 * isub + l15) * CQ_ + quad * 8 + kh * 32);

    float lacc[2] = {0.f, 0.f};
    f32x4 acc[4][2];   // [isub: i=16isub+quad*4+r][csub: c=32wc+16csub+l15]
    #pragma unroll
    for (int a = 0; a < 4; ++a)
        #pragma unroll
        for (int b = 0; b < 2; ++b) acc[a][b] = (f32x4){0.f, 0.f, 0.f, 0.f};

    // K A-frag prefetch for iter 0 (j = 16*jsub + l15)
    half8 kf[2];
    #pragma unroll
    for (int kh = 0; kh < 2; ++kh)
        kf[kh] = *(const half8*)(kp + (size_t)(16 * jsub + l15) * CQ_ + quad * 8 + kh * 32);

    // swizzled Pt addressing: phys_byte = row*128 + (col_byte ^ ((row&7)<<4))
    unsigned char* ptb0 = (unsigned char*)&Pt[0][0];
    unsigned char* ptb1 = (unsigned char*)&Pt[1][0];

    for (int jt = 0; jt < N_; jt += 64) {
        unsigned char* ptw = ((jt >> 6) & 1) ? ptb1 : ptb0;
        // V B-frags for this iter (consumed after barrier; latency hidden by S,
        // and NOT drained at the barrier anymore)
        short8 vf[2][2];
        #pragma unroll
        for (int csub = 0; csub < 2; ++csub)
            #pragma unroll
            for (int kh = 0; kh < 2; ++kh)
                vf[csub][kh] = *(const short8*)(
                    vp + (size_t)(32 * wc + 16 * csub + l15) * N_ + jt + quad * 8 + kh * 32);
        // K prefetch for next iter (rides through the barrier: counted vmcnt)
        int jn = (jt + 64 < N_) ? jt + 64 : 0;
        half8 kn0 = *(const half8*)(kp + (size_t)(jn + 16 * jsub + l15) * CQ_ + quad * 8);
        half8 kn1 = *(const half8*)(kp + (size_t)(jn + 16 * jsub + l15) * CQ_ + quad * 8 + 32);

        // ---- S: S^T[j=16jsub+quad*4+r][i=32ihalf+16isub+l15] ----
        f32x4 sacc[2];
        sacc[0] = (f32x4){0.f, 0.f, 0.f, 0.f};
        sacc[1] = (f32x4){0.f, 0.f, 0.f, 0.f};
        #pragma unroll
        for (int kh = 0; kh < 2; ++kh)
            #pragma unroll
            for (int isub = 0; isub < 2; ++isub)
                sacc[isub] = __builtin_amdgcn_mfma_f32_16x16x32_f16(
                    kf[kh], qf[isub][kh], sacc[isub], 0, 0, 0);

        // p = exp(s - SHIFT); accumulate l; write P[i][j] (bf16, swizzled b64)
        #pragma unroll
        for (int isub = 0; isub < 2; ++isub) {
            f32x4 p;
            p.x = __expf(sacc[isub].x - SHIFT);
            p.y = __expf(sacc[isub].y - SHIFT);
            p.z = __expf(sacc[isub].z - SHIFT);
            p.w = __expf(sacc[isub].w - SHIFT);
            lacc[isub] += p.x + p.y + p.z + p.w;
            ushort4 pbv;
            pbv.x = f2bf(p.x); pbv.y = f2bf(p.y); pbv.z = f2bf(p.z); pbv.w = f2bf(p.w);
            int row = 32 * ihalf + 16 * isub + l15;
            int cb  = (32 * jsub + 8 * quad) ^ ((row & 7) << 4);
            *(ushort4*)(ptw + row * 128 + cb) = pbv;
        }
        kf[0] = kn0; kf[1] = kn1;

        // ---- counted barrier: drain LDS only; K/V loads stay in flight ----
        asm volatile("s_waitcnt lgkmcnt(0)" ::: "memory");
        __builtin_amdgcn_sched_barrier(0);
        __builtin_amdgcn_s_barrier();
        __builtin_amdgcn_sched_barrier(0);

        // ---- PV: O^T[i=16is2+quad*4+r][c=32wc+16csub+l15] ----
        short8 ap[4][2];
        #pragma unroll
        for (int is2 = 0; is2 < 4; ++is2)
            #pragma unroll
            for (int kh = 0; kh < 2; ++kh) {
                int row = 16 * is2 + l15;
                int cb  = (quad * 16 + kh * 64) ^ ((row & 7) << 4);
                ap[is2][kh] = *(const short8*)(ptw + row * 128 + cb);
            }
        #pragma unroll
        for (int kh = 0; kh < 2; ++kh)
            #pragma unroll
            for (int is2 = 0; is2 < 4; ++is2)
                #pragma unroll
                for (int csub = 0; csub < 2; ++csub)
                    acc[is2][csub] = __builtin_amdgcn_mfma_f32_16x16x32_bf16(
                        ap[is2][kh], vf[csub][kh], acc[is2][csub], 0, 0, 0);
    }

    // ---- l reduction (once): quad-shfl then cross-jsub via LDS ----
    #pragma unroll
    for (int isub = 0; isub < 2; ++isub) {
        float t = lacc[isub];
        t += __shfl_xor(t, 16);
        t += __shfl_xor(t, 32);
        if (quad == 0)
            lsum[(32 * ihalf + 16 * isub + l15) * 4 + jsub] = t;
    }
    __syncthreads();

    const float gamma = gamma_p[0];
    const float* inp = (s ? in2 : in1) + (size_t)bb * C_ * N_;
    float* op = out + (size_t)bs * C_ * N_;
    #pragma unroll
    for (int isub = 0; isub < 4; ++isub) {
        float inv[4];
        #pragma unroll
        for (int r = 0; r < 4; ++r) {
            f32x4 t = *(f32x4*)(&lsum[(16 * isub + quad * 4 + r) * 4]);
            inv[r] = 1.0f / (t.x + t.y + t.z + t.w);
        }
        #pragma unroll
        for (int csub = 0; csub < 2; ++csub) {
            int c = 32 * wc + 16 * csub + l15;
            #pragma unroll
            for (int r = 0; r < 4; ++r) {
                int i = q0 + 16 * isub + quad * 4 + r;
                size_t idx = (size_t)c * N_ + i;
                op[idx] = gamma * acc[isub][csub][r] * inv[r] + inp[idx];
            }
        }
    }
}

// ---------------------------------------------------------------------------
extern "C" void kernel_launch(void* const* d_in, const int* in_sizes, int n_in,
                              void* d_out, int out_size, void* d_ws, size_t ws_size,
                              hipStream_t stream)
{
    const float* in1 = (const float*)d_in[0];
    const float* in2 = (const float*)d_in[1];
    const float* q1w = (const float*)d_in[2];
    const float* q1b = (const float*)d_in[3];
    const float* k1w = (const float*)d_in[4];
    const float* k1b = (const float*)d_in[5];
    const float* v1w = (const float*)d_in[6];
    const float* v1b = (const float*)d_in[7];
    const float* q2w = (const float*)d_in[8];
    const float* q2b = (const float*)d_in[9];
    const float* k2w = (const float*)d_in[10];
    const float* k2b = (const float*)d_in[11];
    const float* v2w = (const float*)d_in[12];
    const float* v2b = (const float*)d_in[13];
    const float* gamma = (const float*)d_in[22];
    float* out = (float*)d_out;

    // ws: wb f16 196608 | q[4][4096][64] f16 | k same | v[4][256][4096] bf16
    _Float16* wb   = (_Float16*)d_ws;
    _Float16* q_ws = wb + 196608;
    _Float16* k_ws = q_ws + (size_t)4 * N_ * CQ_;
    unsigned short* v_ws = (unsigned short*)(k_ws + (size_t)4 * N_ * CQ_);

    wconv_kernel<<<dim3(192), 256, 0, stream>>>(q1w, k1w, v1w, q2w, k2w, v2w, wb);
    proj_kernel<<<dim3(64, 4), 512, 0, stream>>>(
        in1, in2, wb, q1b, k1b, v1b, q2b, k2b, v2b, q_ws, k_ws, v_ws);
    flash_kernel<<<dim3(256), 512, 0, stream>>>(q_ws, k_ws, v_ws, in1, in2, gamma, out);
}

// Round 3
// 219.799 us; speedup vs baseline: 1.3803x; 1.0115x over previous
//
#include <hip/hip_runtime.h>
#include <math.h>

// Problem constants
constexpr int B_  = 2;
constexpr int C_  = 256;
constexpr int CQ_ = 64;
constexpr int N_  = 4096;  // 64*64

typedef __attribute__((ext_vector_type(8))) short     short8;  // 8 bf16
typedef __attribute__((ext_vector_type(8))) _Float16  half8;   // 8 f16
typedef __attribute__((ext_vector_type(4))) float     f32x4;   // MFMA C/D

constexpr float SHIFT = 24.0f;   // static softmax shift (exact: shift-invariance)

static __device__ __forceinline__ unsigned short f2bf(float x) {
    union { float f; unsigned u; } v; v.f = x;
    unsigned r = (v.u + 0x7FFFu + ((v.u >> 16) & 1u)) >> 16;  // RNE
    return (unsigned short)r;
}

// ---------------------------------------------------------------------------
// Weight convert: fp32 -> f16, concat [q1|k1|v1|q2|k2|v2] (96K elems/stream)
// ---------------------------------------------------------------------------
__global__ __launch_bounds__(256)
void wconv_kernel(const float* __restrict__ q1w, const float* __restrict__ k1w,
                  const float* __restrict__ v1w, const float* __restrict__ q2w,
                  const float* __restrict__ k2w, const float* __restrict__ v2w,
                  _Float16* __restrict__ wb)
{
    int i = (blockIdx.x * 256 + threadIdx.x) * 4;   // grid 192 -> 196608 elems
    const float* src;
    int off;
    if      (i < 16384)  { src = q1w; off = 0; }
    else if (i < 32768)  { src = k1w; off = 16384; }
    else if (i < 98304)  { src = v1w; off = 32768; }
    else if (i < 114688) { src = q2w; off = 98304; }
    else if (i < 131072) { src = k2w; off = 114688; }
    else                 { src = v2w; off = 131072; }
    float4 f = *(const float4*)(src + (i - off));
    _Float16 h0 = (_Float16)f.x, h1 = (_Float16)f.y;
    _Float16 h2 = (_Float16)f.z, h3 = (_Float16)f.w;
    ushort4 u;
    u.x = *(unsigned short*)&h0; u.y = *(unsigned short*)&h1;
    u.z = *(unsigned short*)&h2; u.w = *(unsigned short*)&h3;
    *(ushort4*)((unsigned short*)wb + i) = u;
}

// ---------------------------------------------------------------------------
// Fused QKV projection (MFMA, f16 inputs, fp32 accum).  (round-0 structure)
// ---------------------------------------------------------------------------
__global__ __launch_bounds__(512)
void proj_kernel(const float* __restrict__ in1, const float* __restrict__ in2,
                 const _Float16* __restrict__ wb,
                 const float* __restrict__ q1b, const float* __restrict__ k1b,
                 const float* __restrict__ v1b, const float* __restrict__ q2b,
                 const float* __restrict__ k2b, const float* __restrict__ v2b,
                 _Float16* __restrict__ q_ws, _Float16* __restrict__ k_ws,
                 unsigned short* __restrict__ v_ws)
{
    __shared__ _Float16 Xs[64 * 264];
    const int bs = blockIdx.y, s = bs >> 1, bb = bs & 1;
    const int n0 = blockIdx.x * 64;
    const float* x = (s ? in2 : in1) + (size_t)bb * C_ * N_;
    const int tid = threadIdx.x;
    const int lane = tid & 63, wave = tid >> 6, quad = lane >> 4, l15 = lane & 15;

    #pragma unroll
    for (int rep = 0; rep < 8; ++rep) {
        int idx = rep * 512 + tid;
        int c = idx >> 4, ng = idx & 15;
        float4 f = *(const float4*)(x + (size_t)c * N_ + n0 + ng * 4);
        Xs[(ng * 4 + 0) * 264 + c] = (_Float16)f.x;
        Xs[(ng * 4 + 1) * 264 + c] = (_Float16)f.y;
        Xs[(ng * 4 + 2) * 264 + c] = (_Float16)f.z;
        Xs[(ng * 4 + 3) * 264 + c] = (_Float16)f.w;
    }
    __syncthreads();

    const _Float16* wqs = wb + (size_t)s * 98304;
    const _Float16* wks = wqs + 16384;
    const _Float16* wvs = wks + 16384;

    // ---- Q/K: waves 0-3 -> Q, 4-7 -> K; n-block = wave&3 ----
    {
        const int m = wave >> 2, nb = wave & 3;
        const _Float16* W = m ? wks : wqs;
        const float* bias = m ? (s ? k2b : k1b) : (s ? q2b : q1b);
        _Float16* outp = (m ? k_ws : q_ws) + (size_t)bs * N_ * CQ_;
        half8 af[8];
        #pragma unroll
        for (int kh = 0; kh < 8; ++kh)
            af[kh] = *(const half8*)(&Xs[(16 * nb + l15) * 264 + quad * 8 + kh * 32]);
        f32x4 a4[4];
        #pragma unroll
        for (int o = 0; o < 4; ++o) a4[o] = (f32x4){0.f, 0.f, 0.f, 0.f};
        #pragma unroll
        for (int kh = 0; kh < 8; ++kh)
            #pragma unroll
            for (int o = 0; o < 4; ++o) {
                half8 bf = *(const half8*)(W + (size_t)(16 * o + l15) * C_ + quad * 8 + kh * 32);
                a4[o] = __builtin_amdgcn_mfma_f32_16x16x32_f16(af[kh], bf, a4[o], 0, 0, 0);
            }
        #pragma unroll
        for (int o = 0; o < 4; ++o) {
            float bv = bias[16 * o + l15];
            #pragma unroll
            for (int r = 0; r < 4; ++r) {
                int n = n0 + 16 * nb + quad * 4 + r;
                outp[(size_t)n * CQ_ + 16 * o + l15] = (_Float16)(a4[o][r] + bv);
            }
        }
    }

    // ---- V: wave owns o-block 32*wave .. +31 ----
    {
        const float* vb = s ? v2b : v1b;
        unsigned short* outp = v_ws + (size_t)bs * C_ * N_;
        f32x4 v4[2][4];
        #pragma unroll
        for (int o = 0; o < 2; ++o)
            #pragma unroll
            for (int nt = 0; nt < 4; ++nt) v4[o][nt] = (f32x4){0.f, 0.f, 0.f, 0.f};
        #pragma unroll
        for (int kh = 0; kh < 8; ++kh) {
            half8 bf[4], af[2];
            #pragma unroll
            for (int nt = 0; nt < 4; ++nt)
                bf[nt] = *(const half8*)(&Xs[(16 * nt + l15) * 264 + quad * 8 + kh * 32]);
            #pragma unroll
            for (int o = 0; o < 2; ++o)
                af[o] = *(const half8*)(wvs + (size_t)(32 * wave + 16 * o + l15) * C_ + quad * 8 + kh * 32);
            #pragma unroll
            for (int o = 0; o < 2; ++o)
                #pragma unroll
                for (int nt = 0; nt < 4; ++nt)
                    v4[o][nt] = __builtin_amdgcn_mfma_f32_16x16x32_f16(af[o], bf[nt], v4[o][nt], 0, 0, 0);
        }
        #pragma unroll
        for (int o = 0; o < 2; ++o)
            #pragma unroll
            for (int r = 0; r < 4; ++r) {
                int c = 32 * wave + 16 * o + quad * 4 + r;
                float bv = vb[c];
                #pragma unroll
                for (int nt = 0; nt < 4; ++nt)
                    outp[(size_t)c * N_ + n0 + 16 * nt + l15] = f2bf(v4[o][nt][r] + bv);
            }
    }
}

// ---------------------------------------------------------------------------
// MFMA flash attention, v4: software-pipelined phases.
// v3 post-mortem: swizzle cut bank conflicts 5x, counted barrier removed the
// vmcnt drain -- NEITHER moved time (102us flat).  The limiter is the serial
// phase chain S->exp->write->barrier->read->PV with all waves in lockstep
// (MfmaUtil 17% + VALUBusy 20% in disjoint slices).
// v4 pipelines across the barrier: after barrier(j), do {read P(j); PV(j)}
// [matrix+LDS] || {S(j+1); exp(j+1); write P(j+1)} [matrix+VALU] || issue
// V(j+1)/K(j+2) loads.  Ping-pong registers are named (kfA/kfB, vfA/vfB) via
// manual unroll-by-2 -- no copies, no forced vmcnt drain (rule: copies of
// fresh loads forced vmcnt(0) pre-barrier in v0-v3).
// WG = 512 thr / 8 waves, TQ=64, TJ=64, grid 256.
// S waves: jsub=w&3, ihalf=w>>2 (S^T[16j][32i]).  PV waves: wc=w (64i x 32c).
// ---------------------------------------------------------------------------
__global__ __launch_bounds__(512)
void flash_kernel(const _Float16* __restrict__ qg,        // [bs][n][64] f16
                  const _Float16* __restrict__ kg,        // [bs][n][64] f16
                  const unsigned short* __restrict__ vg,  // [bs][c][n] bf16
                  const float* __restrict__ in1, const float* __restrict__ in2,
                  const float* __restrict__ gamma_p, float* __restrict__ out)
{
    __shared__ unsigned short Pt[2][64 * 64];   // swizzled, 128 B/row
    __shared__ float lsum[64 * 4];

    const int tid  = threadIdx.x;
    const int lane = tid & 63;
    const int wave = tid >> 6;
    const int quad = lane >> 4;
    const int l15  = lane & 15;
    const int bs   = blockIdx.x & 3;        // one bs per XCD-pair (L2 locality)
    const int q0   = (blockIdx.x >> 2) * 64;
    const int s = bs >> 1, bb = bs & 1;
    const int jsub  = wave & 3;
    const int ihalf = wave >> 2;
    const int wc    = wave;                 // PV: c-block 32*wc

    const _Float16* qp = qg + (size_t)bs * N_ * CQ_;
    const _Float16* kp = kg + (size_t)bs * N_ * CQ_;
    const unsigned short* vp = vg + (size_t)bs * C_ * N_;

    unsigned char* ptb0 = (unsigned char*)&Pt[0][0];
    unsigned char* ptb1 = (unsigned char*)&Pt[1][0];

    // loop-invariant lane bases
    const _Float16* kRow = kp + (size_t)(16 * jsub + l15) * CQ_ + quad * 8;      // + t*4096
    const unsigned short* vRow0 = vp + (size_t)(32 * wc + l15) * N_ + quad * 8;  // + t*64
    const unsigned short* vRow1 = vp + (size_t)(32 * wc + 16 + l15) * N_ + quad * 8;

    // persistent Q B-frags (i = 32*ihalf + 16*isub + l15)
    half8 qf[2][2];
    #pragma unroll
    for (int isub = 0; isub < 2; ++isub)
        #pragma unroll
        for (int kh = 0; kh < 2; ++kh)
            qf[isub][kh] = *(const half8*)(
                qp + (size_t)(q0 + 32 * ihalf + 16 * isub + l15) * CQ_ + quad * 8 + kh * 32);

    float lacc[2] = {0.f, 0.f};
    f32x4 acc[4][2];   // [is2: i=16is2+quad*4+r][csub: c=32wc+16csub+l15]
    #pragma unroll
    for (int a = 0; a < 4; ++a)
        #pragma unroll
        for (int b = 0; b < 2; ++b) acc[a][b] = (f32x4){0.f, 0.f, 0.f, 0.f};

    // ---------------- prologue: K(0),V(0),K(1); S(0); P(0) -> Pt[0] ---------
    half8 kfA[2], kfB[2];
    short8 vfA[2][2], vfB[2][2];
    kfA[0] = *(const half8*)(kRow);
    kfA[1] = *(const half8*)(kRow + 32);
    vfA[0][0] = *(const short8*)(vRow0);
    vfA[0][1] = *(const short8*)(vRow0 + 32);
    vfA[1][0] = *(const short8*)(vRow1);
    vfA[1][1] = *(const short8*)(vRow1 + 32);
    kfB[0] = *(const half8*)(kRow + 4096);
    kfB[1] = *(const half8*)(kRow + 4096 + 32);
    {
        f32x4 sacc[2];
        sacc[0] = (f32x4){0.f, 0.f, 0.f, 0.f};
        sacc[1] = (f32x4){0.f, 0.f, 0.f, 0.f};
        #pragma unroll
        for (int kh = 0; kh < 2; ++kh)
            #pragma unroll
            for (int isub = 0; isub < 2; ++isub)
                sacc[isub] = __builtin_amdgcn_mfma_f32_16x16x32_f16(
                    kfA[kh], qf[isub][kh], sacc[isub], 0, 0, 0);
        #pragma unroll
        for (int isub = 0; isub < 2; ++isub) {
            f32x4 p;
            p.x = __expf(sacc[isub].x - SHIFT);
            p.y = __expf(sacc[isub].y - SHIFT);
            p.z = __expf(sacc[isub].z - SHIFT);
            p.w = __expf(sacc[isub].w - SHIFT);
            lacc[isub] += p.x + p.y + p.z + p.w;
            ushort4 pbv;
            pbv.x = f2bf(p.x); pbv.y = f2bf(p.y); pbv.z = f2bf(p.z); pbv.w = f2bf(p.w);
            int row = 32 * ihalf + 16 * isub + l15;
            int cb  = (32 * jsub + 8 * quad) ^ ((row & 7) << 4);
            *(ushort4*)(ptb0 + row * 128 + cb) = pbv;
        }
    }

// body(J): barrier; read P(J) from PTR; S(J+1) via KS; load KL=K(J+2) if DOK,
//          VL=V(J+1); PV(J) += P(J) x VC; exp(J+1); write P(J+1) -> PTW.
#define FLASH_BODY(J, PTR, PTW, KS, KL, VC, VL, DOK)                          \
  {                                                                           \
    asm volatile("s_waitcnt lgkmcnt(0)" ::: "memory");                        \
    __builtin_amdgcn_sched_barrier(0);                                        \
    __builtin_amdgcn_s_barrier();                                             \
    __builtin_amdgcn_sched_barrier(0);                                        \
    short8 ap[4][2];                                                          \
    _Pragma("unroll")                                                         \
    for (int is2 = 0; is2 < 4; ++is2) {                                       \
      _Pragma("unroll")                                                       \
      for (int kh = 0; kh < 2; ++kh) {                                        \
        int row = 16 * is2 + l15;                                             \
        int cb  = (quad * 16 + kh * 64) ^ ((row & 7) << 4);                   \
        ap[is2][kh] = *(const short8*)((PTR) + row * 128 + cb);               \
      }                                                                       \
    }                                                                         \
    f32x4 sacc[2];                                                            \
    sacc[0] = (f32x4){0.f, 0.f, 0.f, 0.f};                                    \
    sacc[1] = (f32x4){0.f, 0.f, 0.f, 0.f};                                    \
    _Pragma("unroll")                                                         \
    for (int kh = 0; kh < 2; ++kh)                                            \
      _Pragma("unroll")                                                       \
      for (int isub = 0; isub < 2; ++isub)                                    \
        sacc[isub] = __builtin_amdgcn_mfma_f32_16x16x32_f16(                  \
            (KS)[kh], qf[isub][kh], sacc[isub], 0, 0, 0);                     \
    if (DOK) {                                                                \
      (KL)[0] = *(const half8*)(kRow + ((J) + 2) * 4096);                     \
      (KL)[1] = *(const half8*)(kRow + ((J) + 2) * 4096 + 32);                \
    }                                                                         \
    (VL)[0][0] = *(const short8*)(vRow0 + ((J) + 1) * 64);                    \
    (VL)[0][1] = *(const short8*)(vRow0 + ((J) + 1) * 64 + 32);               \
    (VL)[1][0] = *(const short8*)(vRow1 + ((J) + 1) * 64);                    \
    (VL)[1][1] = *(const short8*)(vRow1 + ((J) + 1) * 64 + 32);               \
    __builtin_amdgcn_s_setprio(1);                                            \
    _Pragma("unroll")                                                         \
    for (int kh = 0; kh < 2; ++kh)                                            \
      _Pragma("unroll")                                                       \
      for (int is2 = 0; is2 < 4; ++is2)                                       \
        _Pragma("unroll")                                                     \
        for (int csub = 0; csub < 2; ++csub)                                  \
          acc[is2][csub] = __builtin_amdgcn_mfma_f32_16x16x32_bf16(           \
              ap[is2][kh], (VC)[csub][kh], acc[is2][csub], 0, 0, 0);          \
    __builtin_amdgcn_s_setprio(0);                                            \
    _Pragma("unroll")                                                         \
    for (int isub = 0; isub < 2; ++isub) {                                    \
      f32x4 p;                                                                \
      p.x = __expf(sacc[isub].x - SHIFT);                                     \
      p.y = __expf(sacc[isub].y - SHIFT);                                     \
      p.z = __expf(sacc[isub].z - SHIFT);                                     \
      p.w = __expf(sacc[isub].w - SHIFT);                                     \
      lacc[isub] += p.x + p.y + p.z + p.w;                                    \
      ushort4 pbv;                                                            \
      pbv.x = f2bf(p.x); pbv.y = f2bf(p.y);                                   \
      pbv.z = f2bf(p.z); pbv.w = f2bf(p.w);                                   \
      int row = 32 * ihalf + 16 * isub + l15;                                 \
      int cb  = (32 * jsub + 8 * quad) ^ ((row & 7) << 4);                    \
      *(ushort4*)((PTW) + row * 128 + cb) = pbv;                              \
    }                                                                         \
  }

    // main loop: bodies j=0..61 (ping-pong), then j=62, then consume-only j=63
    for (int it = 0; it < 31; ++it) {
        FLASH_BODY(2 * it,     ptb0, ptb1, kfB, kfA, vfA, vfB, true);
        FLASH_BODY(2 * it + 1, ptb1, ptb0, kfA, kfB, vfB, vfA, true);
    }
    FLASH_BODY(62, ptb0, ptb1, kfB, kfA, vfA, vfB, false);
#undef FLASH_BODY

    // final consume: PV(63) from Pt[1] with vfB = V(63)
    {
        asm volatile("s_waitcnt lgkmcnt(0)" ::: "memory");
        __builtin_amdgcn_sched_barrier(0);
        __builtin_amdgcn_s_barrier();
        __builtin_amdgcn_sched_barrier(0);
        short8 ap[4][2];
        #pragma unroll
        for (int is2 = 0; is2 < 4; ++is2)
            #pragma unroll
            for (int kh = 0; kh < 2; ++kh) {
                int row = 16 * is2 + l15;
                int cb  = (quad * 16 + kh * 64) ^ ((row & 7) << 4);
                ap[is2][kh] = *(const short8*)(ptb1 + row * 128 + cb);
            }
        #pragma unroll
        for (int kh = 0; kh < 2; ++kh)
            #pragma unroll
            for (int is2 = 0; is2 < 4; ++is2)
                #pragma unroll
                for (int csub = 0; csub < 2; ++csub)
                    acc[is2][csub] = __builtin_amdgcn_mfma_f32_16x16x32_bf16(
                        ap[is2][kh], vfB[csub][kh], acc[is2][csub], 0, 0, 0);
    }

    // ---- l reduction (once): quad-shfl then cross-jsub via LDS ----
    #pragma unroll
    for (int isub = 0; isub < 2; ++isub) {
        float t = lacc[isub];
        t += __shfl_xor(t, 16);
        t += __shfl_xor(t, 32);
        if (quad == 0)
            lsum[(32 * ihalf + 16 * isub + l15) * 4 + jsub] = t;
    }
    __syncthreads();

    const float gamma = gamma_p[0];
    const float* inp = (s ? in2 : in1) + (size_t)bb * C_ * N_;
    float* op = out + (size_t)bs * C_ * N_;
    #pragma unroll
    for (int isub = 0; isub < 4; ++isub) {
        float inv[4];
        #pragma unroll
        for (int r = 0; r < 4; ++r) {
            f32x4 t = *(f32x4*)(&lsum[(16 * isub + quad * 4 + r) * 4]);
            inv[r] = 1.0f / (t.x + t.y + t.z + t.w);
        }
        #pragma unroll
        for (int csub = 0; csub < 2; ++csub) {
            int c = 32 * wc + 16 * csub + l15;
            #pragma unroll
            for (int r = 0; r < 4; ++r) {
                int i = q0 + 16 * isub + quad * 4 + r;
                size_t idx = (size_t)c * N_ + i;
                op[idx] = gamma * acc[isub][csub][r] * inv[r] + inp[idx];
            }
        }
    }
}

// ---------------------------------------------------------------------------
extern "C" void kernel_launch(void* const* d_in, const int* in_sizes, int n_in,
                              void* d_out, int out_size, void* d_ws, size_t ws_size,
                              hipStream_t stream)
{
    const float* in1 = (const float*)d_in[0];
    const float* in2 = (const float*)d_in[1];
    const float* q1w = (const float*)d_in[2];
    const float* q1b = (const float*)d_in[3];
    const float* k1w = (const float*)d_in[4];
    const float* k1b = (const float*)d_in[5];
    const float* v1w = (const float*)d_in[6];
    const float* v1b = (const float*)d_in[7];
    const float* q2w = (const float*)d_in[8];
    const float* q2b = (const float*)d_in[9];
    const float* k2w = (const float*)d_in[10];
    const float* k2b = (const float*)d_in[11];
    const float* v2w = (const float*)d_in[12];
    const float* v2b = (const float*)d_in[13];
    const float* gamma = (const float*)d_in[22];
    float* out = (float*)d_out;

    // ws: wb f16 196608 | q[4][4096][64] f16 | k same | v[4][256][4096] bf16
    _Float16* wb   = (_Float16*)d_ws;
    _Float16* q_ws = wb + 196608;
    _Float16* k_ws = q_ws + (size_t)4 * N_ * CQ_;
    unsigned short* v_ws = (unsigned short*)(k_ws + (size_t)4 * N_ * CQ_);

    wconv_kernel<<<dim3(192), 256, 0, stream>>>(q1w, k1w, v1w, q2w, k2w, v2w, wb);
    proj_kernel<<<dim3(64, 4), 512, 0, stream>>>(
        in1, in2, wb, q1b, k1b, v1b, q2b, k2b, v2b, q_ws, k_ws, v_ws);
    flash_kernel<<<dim3(256), 512, 0, stream>>>(q_ws, k_ws, v_ws, in1, in2, gamma, out);
}